// Round 1
// baseline (779.164 us; speedup 1.0000x reference)
//
#include <hip/hip_runtime.h>

// Problem constants (from reference): V=27, E=64, H=128, B=256, S=512 (both enc/dec)
#define V_ 27
#define E_ 64
#define H_ 128
#define S_ 512

// Fast tanh via exp2-based expf; |err| ~1e-7, far below the 2.8e-2 threshold.
__device__ __forceinline__ float fast_tanhf(float z) {
    float az = fabsf(z);
    float e  = __expf(-2.0f * az);
    float t  = __fdividef(1.0f - e, 1.0f + e);
    return copysignf(t, z);
}

// One block per batch row (256 blocks x 256 threads).
// Thread (half = tid>>7, jj = tid&127): computes partial dot for hidden unit jj
// over k in [half*64, half*64+64), Wh column slice held in registers.
// h double-buffered in LDS; xw_t comes from a 27x128 LDS table T = embed@Wx + b.
// Dense layer (27 logits) pipelined onto half==1 waves during decoder phase B,
// operating on the previous step's h (other LDS buffer) -> no workspace needed.
__global__ __launch_bounds__(256, 1)
void seq2seq_rnn_kernel(const int* __restrict__ enc_ids, const int* __restrict__ dec_ids,
                        const float* __restrict__ embed,
                        const float* __restrict__ enc_Wx, const float* __restrict__ enc_Wh,
                        const float* __restrict__ enc_b,
                        const float* __restrict__ dec_Wx, const float* __restrict__ dec_Wh,
                        const float* __restrict__ dec_b,
                        const float* __restrict__ dense_W, const float* __restrict__ dense_b,
                        float* __restrict__ out) {
    __shared__ __align__(16) float lds_T[2 * V_ * H_];   // [tbl][v][j], 6912 floats
    __shared__ __align__(16) float lds_h[2][H_];         // double-buffered hidden state
    __shared__ __align__(16) float lds_part[2][H_];      // [half][j] split-K partials
    __shared__ __align__(16) float lds_emb[V_ * E_];     // staged embedding (1728 floats)
    __shared__ int lds_ids[2 * S_];                      // enc ids then dec ids for row b

    const int tid  = threadIdx.x;
    const int b    = blockIdx.x;
    const int jj   = tid & (H_ - 1);
    const int half = tid >> 7;

    // ---- setup: stage embed, ids, init h ----
    for (int i = tid; i < V_ * E_; i += 256) lds_emb[i] = embed[i];
    ((int2*)lds_ids)[tid]        = ((const int2*)(enc_ids + b * S_))[tid];  // 256*2 = 512 ints
    ((int2*)(lds_ids + S_))[tid] = ((const int2*)(dec_ids + b * S_))[tid];
    if (tid < H_) lds_h[0][tid] = 0.0f;
    __syncthreads();

    // ---- T tables: T[tbl][v][j] = b[j] + sum_e embed[v][e]*Wx[e][j] ----
    for (int idx = tid; idx < 2 * V_ * H_; idx += 256) {
        int tbl = idx / (V_ * H_);
        int rem = idx - tbl * (V_ * H_);
        int v = rem >> 7;
        int j = rem & (H_ - 1);
        const float* Wx = tbl ? dec_Wx : enc_Wx;
        const float* bb = tbl ? dec_b : enc_b;
        float s = bb[j];
        #pragma unroll
        for (int e = 0; e < E_; ++e)
            s = fmaf(lds_emb[v * E_ + e], Wx[e * H_ + j], s);
        lds_T[idx] = s;
    }

    // ---- Wh slice into registers (encoder weights first) ----
    float wh[64];
    #pragma unroll
    for (int k = 0; k < 64; ++k) wh[k] = enc_Wh[(half * 64 + k) * H_ + jj];

    // ---- dense weights for half==1 threads: (vd, qd), qd-th quarter of k ----
    float wd[32];
    float db = 0.0f;
    const int Ld = tid - 128;
    const int vd = Ld >> 2;
    const int qd = Ld & 3;
    if (half == 1 && vd < V_) {
        db = dense_b[vd];
        #pragma unroll
        for (int i = 0; i < 32; ++i) wd[i] = dense_W[(qd * 32 + i) * V_ + vd];
    } else {
        #pragma unroll
        for (int i = 0; i < 32; ++i) wd[i] = 0.0f;
    }

    float* outb = out + b * (S_ * V_);

    __syncthreads();  // T tables + h ready

    // ================= encoder: 512 steps =================
    for (int t = 0; t < S_; ++t) {
        const int cur = t & 1;
        // prefetch xw for this step (only combine waves need it)
        float Tval = 0.0f;
        if (half == 0) {
            int id = lds_ids[t];
            Tval = lds_T[id * H_ + jj];
        }
        // phase A: partial dot over this half's 64 k (h broadcast reads, wave-uniform addr)
        const float4* hb = (const float4*)&lds_h[cur][half * 64];
        float a0 = 0.f, a1 = 0.f, a2 = 0.f, a3 = 0.f;
        #pragma unroll
        for (int k4 = 0; k4 < 16; ++k4) {
            float4 hv = hb[k4];
            a0 = fmaf(hv.x, wh[4 * k4 + 0], a0);
            a1 = fmaf(hv.y, wh[4 * k4 + 1], a1);
            a2 = fmaf(hv.z, wh[4 * k4 + 2], a2);
            a3 = fmaf(hv.w, wh[4 * k4 + 3], a3);
        }
        lds_part[half][jj] = (a0 + a1) + (a2 + a3);
        __syncthreads();
        // phase B: combine + tanh (half 0 covers all 128 j)
        if (half == 0) {
            float z = lds_part[0][jj] + lds_part[1][jj] + Tval;
            lds_h[cur ^ 1][jj] = fast_tanhf(z);
        }
        __syncthreads();
    }

    // swap to decoder recurrent weights (registers private; no sync needed)
    #pragma unroll
    for (int k = 0; k < 64; ++k) wh[k] = dec_Wh[(half * 64 + k) * H_ + jj];

    // ================= decoder: 512 steps (parity continues: enc ended writing lds_h[0]) =================
    for (int t = 0; t < S_; ++t) {
        const int cur = t & 1;
        float Tval = 0.0f;
        if (half == 0) {
            int id = lds_ids[S_ + t];
            Tval = lds_T[V_ * H_ + id * H_ + jj];
        }
        const float4* hb = (const float4*)&lds_h[cur][half * 64];
        float a0 = 0.f, a1 = 0.f, a2 = 0.f, a3 = 0.f;
        #pragma unroll
        for (int k4 = 0; k4 < 16; ++k4) {
            float4 hv = hb[k4];
            a0 = fmaf(hv.x, wh[4 * k4 + 0], a0);
            a1 = fmaf(hv.y, wh[4 * k4 + 1], a1);
            a2 = fmaf(hv.z, wh[4 * k4 + 2], a2);
            a3 = fmaf(hv.w, wh[4 * k4 + 3], a3);
        }
        lds_part[half][jj] = (a0 + a1) + (a2 + a3);
        __syncthreads();
        if (half == 0) {
            float z = lds_part[0][jj] + lds_part[1][jj] + Tval;
            lds_h[cur ^ 1][jj] = fast_tanhf(z);
        } else if (t > 0) {
            // dense for previous decoder output h_{t-1}, sitting in lds_h[cur]
            const float4* hc = (const float4*)&lds_h[cur][qd * 32];
            float d0 = 0.f, d1 = 0.f, d2 = 0.f, d3 = 0.f;
            #pragma unroll
            for (int i4 = 0; i4 < 8; ++i4) {
                float4 hv = hc[i4];
                d0 = fmaf(hv.x, wd[4 * i4 + 0], d0);
                d1 = fmaf(hv.y, wd[4 * i4 + 1], d1);
                d2 = fmaf(hv.z, wd[4 * i4 + 2], d2);
                d3 = fmaf(hv.w, wd[4 * i4 + 3], d3);
            }
            float s = (d0 + d1) + (d2 + d3);
            s += __shfl_xor(s, 1);
            s += __shfl_xor(s, 2);
            if (qd == 0 && vd < V_) outb[(t - 1) * V_ + vd] = s + db;
        }
        __syncthreads();
    }

    // epilogue: dense for final decoder output (t=511 wrote lds_h[0])
    if (half == 1) {
        const float4* hc = (const float4*)&lds_h[0][qd * 32];
        float d0 = 0.f, d1 = 0.f, d2 = 0.f, d3 = 0.f;
        #pragma unroll
        for (int i4 = 0; i4 < 8; ++i4) {
            float4 hv = hc[i4];
            d0 = fmaf(hv.x, wd[4 * i4 + 0], d0);
            d1 = fmaf(hv.y, wd[4 * i4 + 1], d1);
            d2 = fmaf(hv.z, wd[4 * i4 + 2], d2);
            d3 = fmaf(hv.w, wd[4 * i4 + 3], d3);
        }
        float s = (d0 + d1) + (d2 + d3);
        s += __shfl_xor(s, 1);
        s += __shfl_xor(s, 2);
        if (qd == 0 && vd < V_) outb[(S_ - 1) * V_ + vd] = s + db;
    }
}

extern "C" void kernel_launch(void* const* d_in, const int* in_sizes, int n_in,
                              void* d_out, int out_size, void* d_ws, size_t ws_size,
                              hipStream_t stream) {
    const int*   enc_ids = (const int*)d_in[0];
    const int*   dec_ids = (const int*)d_in[1];
    const float* embed   = (const float*)d_in[2];
    const float* enc_Wx  = (const float*)d_in[3];
    const float* enc_Wh  = (const float*)d_in[4];
    const float* enc_b   = (const float*)d_in[5];
    const float* dec_Wx  = (const float*)d_in[6];
    const float* dec_Wh  = (const float*)d_in[7];
    const float* dec_b   = (const float*)d_in[8];
    const float* dense_W = (const float*)d_in[9];
    const float* dense_b = (const float*)d_in[10];
    float* out = (float*)d_out;

    hipLaunchKernelGGL(seq2seq_rnn_kernel, dim3(256), dim3(256), 0, stream,
                       enc_ids, dec_ids, embed, enc_Wx, enc_Wh, enc_b,
                       dec_Wx, dec_Wh, dec_b, dense_W, dense_b, out);
}

// Round 2
// 592.819 us; speedup vs baseline: 1.3143x; 1.3143x over previous
//
#include <hip/hip_runtime.h>

// Problem constants: V=27, E=64, H=128, B=256, S=512 (enc and dec)
#define V_ 27
#define E_ 64
#define H_ 128
#define S_ 512

__device__ __forceinline__ float fast_tanhf(float z) {
    float az = fabsf(z);
    float e  = __expf(-2.0f * az);
    float t  = __fdividef(1.0f - e, 1.0f + e);
    return copysignf(t, z);
}

// One block per batch row: 256 blocks x 512 threads (8 waves).
// Recurrence: wave w owns hidden units j in [16w,16w+16); lane l: j=16w+(l&15),
// k-quarter q=l>>4 (32 k each). Split-k reduced with 2 shfl_xor (no LDS/barrier).
// ONE __syncthreads per step. Dense (27 logits) piggybacks on the same step,
// reading the step's INPUT buffer h[p] (= previous decoder output state):
// thread tid: v = tid>>4 (27 of 32 used), k-chunk kq = tid&15 (8 k each),
// reduced with 4 shfl_xor.
__global__ __launch_bounds__(512, 1)
void seq2seq_rnn_kernel(const int* __restrict__ enc_ids, const int* __restrict__ dec_ids,
                        const float* __restrict__ embed,
                        const float* __restrict__ enc_Wx, const float* __restrict__ enc_Wh,
                        const float* __restrict__ enc_b,
                        const float* __restrict__ dec_Wx, const float* __restrict__ dec_Wh,
                        const float* __restrict__ dec_b,
                        const float* __restrict__ dense_W, const float* __restrict__ dense_b,
                        float* __restrict__ out) {
    __shared__ __align__(16) float lds_T[2 * V_ * H_];   // xw tables: [tbl][v][j]
    __shared__ __align__(16) float lds_h[2][H_];         // double-buffered hidden state
    __shared__ __align__(16) float lds_emb[V_ * E_];
    __shared__ int lds_ids[2 * S_];

    const int tid  = threadIdx.x;
    const int b    = blockIdx.x;
    const int w    = tid >> 6;            // wave 0..7
    const int lane = tid & 63;
    const int jj   = (w << 4) | (lane & 15);  // hidden unit 0..127
    const int q    = lane >> 4;               // k-quarter 0..3
    const int vd   = tid >> 4;                // dense output 0..31 (27 used)
    const int kq   = tid & 15;                // dense k-chunk of 8

    // ---- stage embed, ids, init h ----
    for (int i = tid; i < V_ * E_; i += 512) lds_emb[i] = embed[i];
    if (tid < 256) ((int2*)lds_ids)[tid] = ((const int2*)(enc_ids + b * S_))[tid];
    else ((int2*)(lds_ids + S_))[tid - 256] = ((const int2*)(dec_ids + b * S_))[tid - 256];
    if (tid < H_) lds_h[0][tid] = 0.0f;
    __syncthreads();

    // ---- T tables: T[tbl][v][j] = b[j] + sum_e embed[v][e]*Wx[e][j] ----
    for (int idx = tid; idx < 2 * V_ * H_; idx += 512) {
        int tbl = idx / (V_ * H_);
        int rem = idx - tbl * (V_ * H_);
        int v = rem >> 7;
        int j = rem & (H_ - 1);
        const float* Wx = tbl ? dec_Wx : enc_Wx;
        const float* bb = tbl ? dec_b : enc_b;
        float s = bb[j];
        #pragma unroll
        for (int e = 0; e < E_; ++e)
            s = fmaf(lds_emb[v * E_ + e], Wx[e * H_ + j], s);
        lds_T[idx] = s;
    }

    // ---- Wh slice into registers: wh[k2] = Wh[32q+k2][jj] ----
    float wh[32];
    #pragma unroll
    for (int k = 0; k < 32; ++k) wh[k] = enc_Wh[(32 * q + k) * H_ + jj];

    // ---- dense weights: wd[i] = dense_W[8kq+i][vd] ----
    float wd[8];
    float db = 0.0f;
    if (vd < V_) {
        db = dense_b[vd];
        #pragma unroll
        for (int i = 0; i < 8; ++i) wd[i] = dense_W[(8 * kq + i) * V_ + vd];
    } else {
        #pragma unroll
        for (int i = 0; i < 8; ++i) wd[i] = 0.0f;
    }

    float* outb = out + b * (S_ * V_);
    __syncthreads();  // T tables ready

    // ================= encoder: 512 steps, 1 barrier each =================
    for (int t = 0; t < S_; ++t) {
        const int p  = t & 1;
        const int id = lds_ids[t];
        float Tv = lds_T[id * H_ + jj];
        const float4* hb = (const float4*)&lds_h[p][q << 5];
        float a0 = 0.f, a1 = 0.f, a2 = 0.f, a3 = 0.f;
        #pragma unroll
        for (int i = 0; i < 8; ++i) {
            float4 hv = hb[i];
            a0 = fmaf(hv.x, wh[4 * i + 0], a0);
            a1 = fmaf(hv.y, wh[4 * i + 1], a1);
            a2 = fmaf(hv.z, wh[4 * i + 2], a2);
            a3 = fmaf(hv.w, wh[4 * i + 3], a3);
        }
        float s = (a0 + a1) + (a2 + a3);
        s += __shfl_xor(s, 16);
        s += __shfl_xor(s, 32);
        float hnew = fast_tanhf(s + Tv);
        if (lane < 16) lds_h[p ^ 1][jj] = hnew;
        __syncthreads();
    }

    // swap recurrent weights to decoder (registers private; barrier above suffices)
    #pragma unroll
    for (int k = 0; k < 32; ++k) wh[k] = dec_Wh[(32 * q + k) * H_ + jj];

    // ================= decoder: 512 steps; dense piggybacked =================
    // Parity continues: encoder ended writing lds_h[0]; decoder t reads lds_h[t&1].
    for (int t = 0; t < S_; ++t) {
        const int p  = t & 1;
        const int id = lds_ids[S_ + t];
        float Tv = lds_T[V_ * H_ + id * H_ + jj];
        const float4* hb = (const float4*)&lds_h[p][q << 5];
        float a0 = 0.f, a1 = 0.f, a2 = 0.f, a3 = 0.f;
        #pragma unroll
        for (int i = 0; i < 8; ++i) {
            float4 hv = hb[i];
            a0 = fmaf(hv.x, wh[4 * i + 0], a0);
            a1 = fmaf(hv.y, wh[4 * i + 1], a1);
            a2 = fmaf(hv.z, wh[4 * i + 2], a2);
            a3 = fmaf(hv.w, wh[4 * i + 3], a3);
        }
        float s = (a0 + a1) + (a2 + a3);
        s += __shfl_xor(s, 16);
        s += __shfl_xor(s, 32);
        float hnew = fast_tanhf(s + Tv);
        if (lane < 16) lds_h[p ^ 1][jj] = hnew;
        // dense on h[p] = output state of decoder step t-1 (valid for t>=1)
        if (t > 0) {
            const float4* hc = (const float4*)&lds_h[p][kq << 3];
            float4 h0 = hc[0], h1 = hc[1];
            float d0 = 0.f, d1 = 0.f;
            d0 = fmaf(h0.x, wd[0], d0); d1 = fmaf(h0.y, wd[1], d1);
            d0 = fmaf(h0.z, wd[2], d0); d1 = fmaf(h0.w, wd[3], d1);
            d0 = fmaf(h1.x, wd[4], d0); d1 = fmaf(h1.y, wd[5], d1);
            d0 = fmaf(h1.z, wd[6], d0); d1 = fmaf(h1.w, wd[7], d1);
            float d = d0 + d1;
            d += __shfl_xor(d, 1);
            d += __shfl_xor(d, 2);
            d += __shfl_xor(d, 4);
            d += __shfl_xor(d, 8);
            if (kq == 0 && vd < V_) outb[(t - 1) * V_ + vd] = d + db;
        }
        __syncthreads();
    }

    // epilogue: dense on final state (decoder t=511 wrote lds_h[0]) -> logits[511]
    {
        const float4* hc = (const float4*)&lds_h[0][kq << 3];
        float4 h0 = hc[0], h1 = hc[1];
        float d0 = 0.f, d1 = 0.f;
        d0 = fmaf(h0.x, wd[0], d0); d1 = fmaf(h0.y, wd[1], d1);
        d0 = fmaf(h0.z, wd[2], d0); d1 = fmaf(h0.w, wd[3], d1);
        d0 = fmaf(h1.x, wd[4], d0); d1 = fmaf(h1.y, wd[5], d1);
        d0 = fmaf(h1.z, wd[6], d0); d1 = fmaf(h1.w, wd[7], d1);
        float d = d0 + d1;
        d += __shfl_xor(d, 1);
        d += __shfl_xor(d, 2);
        d += __shfl_xor(d, 4);
        d += __shfl_xor(d, 8);
        if (kq == 0 && vd < V_) outb[(S_ - 1) * V_ + vd] = d + db;
    }
}

extern "C" void kernel_launch(void* const* d_in, const int* in_sizes, int n_in,
                              void* d_out, int out_size, void* d_ws, size_t ws_size,
                              hipStream_t stream) {
    const int*   enc_ids = (const int*)d_in[0];
    const int*   dec_ids = (const int*)d_in[1];
    const float* embed   = (const float*)d_in[2];
    const float* enc_Wx  = (const float*)d_in[3];
    const float* enc_Wh  = (const float*)d_in[4];
    const float* enc_b   = (const float*)d_in[5];
    const float* dec_Wx  = (const float*)d_in[6];
    const float* dec_Wh  = (const float*)d_in[7];
    const float* dec_b   = (const float*)d_in[8];
    const float* dense_W = (const float*)d_in[9];
    const float* dense_b = (const float*)d_in[10];
    float* out = (float*)d_out;

    hipLaunchKernelGGL(seq2seq_rnn_kernel, dim3(256), dim3(512), 0, stream,
                       enc_ids, dec_ids, embed, enc_Wx, enc_Wh, enc_b,
                       dec_Wx, dec_Wh, dec_b, dense_W, dense_b, out);
}

// Round 3
// 472.559 us; speedup vs baseline: 1.6488x; 1.2545x over previous
//
#include <hip/hip_runtime.h>

// Problem constants: V=27, E=64, H=128, B=256, S=512 (enc and dec)
#define V_ 27
#define E_ 64
#define H_ 128
#define S_ 512
#define HPAD 144   // h stored padded: word(k) = k + 4*(k>>5)  (+4 words per 32-group)

// Barrier WITHOUT vmcnt drain: LDS visibility only (lgkmcnt(0) + s_barrier).
// Global stores issued in the loop stay in flight — never on the critical path.
#define BAR() asm volatile("s_waitcnt lgkmcnt(0)\n\ts_barrier" ::: "memory")

// sum over quad lanes {l, l^1, l^2, l^3} via two DPP quad_perm adds (VALU-only)
__device__ __forceinline__ float quad_add2(float x) {
    int y1 = __builtin_amdgcn_update_dpp(0, __builtin_bit_cast(int, x),
                                         0xB1 /*[1,0,3,2]*/, 0xF, 0xF, true);
    x += __builtin_bit_cast(float, y1);
    int y2 = __builtin_amdgcn_update_dpp(0, __builtin_bit_cast(int, x),
                                         0x4E /*[2,3,0,1]*/, 0xF, 0xF, true);
    x += __builtin_bit_cast(float, y2);
    return x;
}
__device__ __forceinline__ float swz_add_xor4(float x) {
    int y = __builtin_amdgcn_ds_swizzle(__builtin_bit_cast(int, x), 0x101F);
    return x + __builtin_bit_cast(float, y);
}
__device__ __forceinline__ float swz_add_xor8(float x) {
    int y = __builtin_amdgcn_ds_swizzle(__builtin_bit_cast(int, x), 0x201F);
    return x + __builtin_bit_cast(float, y);
}

// tanh(z) = 1 - 2/(e^{2z}+1); fp32-stable at both extremes (inf -> 1, 0 -> -1).
__device__ __forceinline__ float fast_tanhf(float z) {
    float e = __expf(2.0f * z);
    return 1.0f - __fdividef(2.0f, e + 1.0f);
}

// One step of the recurrence (+ optional piggybacked dense on hsrc).
// Lane mapping: wave w owns j in [16w,16w+16); lane l: jj = 16w + (l>>2),
// k-quarter q = l&3 (32 k each); quad-reduce via DPP; (l&3)==0 writes h.
// Dense: vd = tid>>4 (27 of 32 used), kq = tid&15 (8 k each); reduce DPP+swizzle.
template<bool DENSE>
__device__ __forceinline__ void rnn_step(
    const float* __restrict__ hsrc, float* __restrict__ hdst,
    const float* __restrict__ wh, const float* __restrict__ wd, float db,
    const int* __restrict__ idp,      // &ids[t]  (idp[2] prefetched for t+2)
    const float* __restrict__ Tb,     // xw table base for this phase
    int jj, int q, int lane, int kq, int wjj,
    int& id_b, float& Tv,             // software pipeline: id_{t+1}, Tv_t
    bool dostore, float* __restrict__ outp)
{
    int   id_n = idp[2];              // prefetch id_{t+2}
    float Tv_n = Tb[id_b * H_ + jj];  // prefetch Tv_{t+1}
    const float4* hb = (const float4*)(hsrc + q * 36);
    float a0 = 0.f, a1 = 0.f, a2 = 0.f, a3 = 0.f;
    #pragma unroll
    for (int i = 0; i < 8; ++i) {
        float4 hv = hb[i];
        a0 = fmaf(hv.x, wh[4 * i + 0], a0);
        a1 = fmaf(hv.y, wh[4 * i + 1], a1);
        a2 = fmaf(hv.z, wh[4 * i + 2], a2);
        a3 = fmaf(hv.w, wh[4 * i + 3], a3);
    }
    float s = (a0 + a1) + (a2 + a3);
    s = quad_add2(s);
    float hnew = fast_tanhf(s + Tv);
    if ((lane & 3) == 0) hdst[wjj] = hnew;
    if (DENSE) {
        const float4* hc = (const float4*)(hsrc + kq * 8 + ((kq >> 2) << 2));
        float4 u0 = hc[0], u1 = hc[1];
        float d0 = 0.f, d1 = 0.f;
        d0 = fmaf(u0.x, wd[0], d0); d1 = fmaf(u0.y, wd[1], d1);
        d0 = fmaf(u0.z, wd[2], d0); d1 = fmaf(u0.w, wd[3], d1);
        d0 = fmaf(u1.x, wd[4], d0); d1 = fmaf(u1.y, wd[5], d1);
        d0 = fmaf(u1.z, wd[6], d0); d1 = fmaf(u1.w, wd[7], d1);
        float d = quad_add2(d0 + d1);
        d = swz_add_xor4(d);
        d = swz_add_xor8(d);
        if (dostore) outp[0] = d + db;   // vmcnt never drained by BAR
    }
    BAR();
    id_b = id_n;
    Tv   = Tv_n;
}

__global__ __launch_bounds__(512, 1)
void seq2seq_rnn_kernel(const int* __restrict__ enc_ids, const int* __restrict__ dec_ids,
                        const float* __restrict__ embed,
                        const float* __restrict__ enc_Wx, const float* __restrict__ enc_Wh,
                        const float* __restrict__ enc_b,
                        const float* __restrict__ dec_Wx, const float* __restrict__ dec_Wh,
                        const float* __restrict__ dec_b,
                        const float* __restrict__ dense_W, const float* __restrict__ dense_b,
                        float* __restrict__ out) {
    __shared__ __align__(16) float lds_T[2 * V_ * H_];   // xw tables (unpadded; broadcast reads)
    __shared__ __align__(16) float lds_h0[HPAD];         // padded h buffers
    __shared__ __align__(16) float lds_h1[HPAD];
    __shared__ __align__(16) float lds_emb[V_ * E_];
    __shared__ __align__(16) int   lds_ids[2 * S_ + 2];  // +2 pad for prefetch

    const int tid  = threadIdx.x;
    const int b    = blockIdx.x;
    const int lane = tid & 63;
    const int w    = tid >> 6;
    const int jj   = (w << 4) | (lane >> 2);   // hidden unit 0..127
    const int q    = lane & 3;                 // k-quarter
    const int wjj  = jj + ((jj >> 5) << 2);    // padded word index of jj
    const int vd   = tid >> 4;                 // dense logit slot (27 of 32 used)
    const int kq   = tid & 15;                 // dense k-chunk of 8

    // ---- stage embed, ids; zero h0 ----
    for (int i = tid; i < V_ * E_; i += 512) lds_emb[i] = embed[i];
    if (tid < 256) ((int2*)lds_ids)[tid] = ((const int2*)(enc_ids + b * S_))[tid];
    else ((int2*)(lds_ids + S_))[tid - 256] = ((const int2*)(dec_ids + b * S_))[tid - 256];
    if (tid < 2) lds_ids[2 * S_ + tid] = 0;
    if (tid < HPAD) lds_h0[tid] = 0.0f;
    __syncthreads();

    // ---- T tables: T[tbl][v][j] = b[j] + sum_e embed[v][e]*Wx[e][j] ----
    for (int idx = tid; idx < 2 * V_ * H_; idx += 512) {
        int tbl = idx / (V_ * H_);
        int rem = idx - tbl * (V_ * H_);
        int v = rem >> 7, j = rem & (H_ - 1);
        const float* Wx = tbl ? dec_Wx : enc_Wx;
        const float* bb = tbl ? dec_b : enc_b;
        float sacc = bb[j];
        #pragma unroll
        for (int e = 0; e < E_; ++e)
            sacc = fmaf(lds_emb[v * E_ + e], Wx[e * H_ + j], sacc);
        lds_T[idx] = sacc;
    }

    // ---- recurrent weights: wh[k] = Wh[32q+k][jj] (encoder first) ----
    float wh[32];
    #pragma unroll
    for (int k = 0; k < 32; ++k) wh[k] = enc_Wh[(32 * q + k) * H_ + jj];

    // ---- dense weights ----
    float wd[8]; float db = 0.0f;
    if (vd < V_) {
        db = dense_b[vd];
        #pragma unroll
        for (int i = 0; i < 8; ++i) wd[i] = dense_W[(8 * kq + i) * V_ + vd];
    } else {
        #pragma unroll
        for (int i = 0; i < 8; ++i) wd[i] = 0.0f;
    }
    const bool dlane = (kq == 0) && (vd < V_);
    float* outb = out + b * (S_ * V_) + vd - V_;   // step-t store target = outb + t*V_
    __syncthreads();  // T tables ready

    // ================= encoder: 512 steps =================
    {
        int   id_b = lds_ids[1];
        float Tv   = lds_T[lds_ids[0] * H_ + jj];
        for (int t = 0; t < S_; t += 2) {
            rnn_step<false>(lds_h0, lds_h1, wh, wd, db, lds_ids + t,     lds_T,
                            jj, q, lane, kq, wjj, id_b, Tv, false, nullptr);
            rnn_step<false>(lds_h1, lds_h0, wh, wd, db, lds_ids + t + 1, lds_T,
                            jj, q, lane, kq, wjj, id_b, Tv, false, nullptr);
        }
    }

    // swap to decoder recurrent weights (registers private)
    #pragma unroll
    for (int k = 0; k < 32; ++k) wh[k] = dec_Wh[(32 * q + k) * H_ + jj];

    // ================= decoder: 512 steps; dense piggybacked =================
    {
        const int*   ids_d = lds_ids + S_;
        const float* Td    = lds_T + V_ * H_;
        int   id_b = ids_d[1];
        float Tv   = Td[ids_d[0] * H_ + jj];
        for (int t = 0; t < S_; t += 2) {
            rnn_step<true>(lds_h0, lds_h1, wh, wd, db, ids_d + t,     Td,
                           jj, q, lane, kq, wjj, id_b, Tv, dlane && (t > 0), outb + t * V_);
            rnn_step<true>(lds_h1, lds_h0, wh, wd, db, ids_d + t + 1, Td,
                           jj, q, lane, kq, wjj, id_b, Tv, dlane, outb + (t + 1) * V_);
        }
    }

    // epilogue: dense on final state (decoder t=511 wrote lds_h0) -> logits[511]
    {
        const float4* hc = (const float4*)(lds_h0 + kq * 8 + ((kq >> 2) << 2));
        float4 u0 = hc[0], u1 = hc[1];
        float d0 = 0.f, d1 = 0.f;
        d0 = fmaf(u0.x, wd[0], d0); d1 = fmaf(u0.y, wd[1], d1);
        d0 = fmaf(u0.z, wd[2], d0); d1 = fmaf(u0.w, wd[3], d1);
        d0 = fmaf(u1.x, wd[4], d0); d1 = fmaf(u1.y, wd[5], d1);
        d0 = fmaf(u1.z, wd[6], d0); d1 = fmaf(u1.w, wd[7], d1);
        float d = quad_add2(d0 + d1);
        d = swz_add_xor4(d);
        d = swz_add_xor8(d);
        if (dlane) (outb + S_ * V_)[0] = d + db;
    }
}

extern "C" void kernel_launch(void* const* d_in, const int* in_sizes, int n_in,
                              void* d_out, int out_size, void* d_ws, size_t ws_size,
                              hipStream_t stream) {
    const int*   enc_ids = (const int*)d_in[0];
    const int*   dec_ids = (const int*)d_in[1];
    const float* embed   = (const float*)d_in[2];
    const float* enc_Wx  = (const float*)d_in[3];
    const float* enc_Wh  = (const float*)d_in[4];
    const float* enc_b   = (const float*)d_in[5];
    const float* dec_Wx  = (const float*)d_in[6];
    const float* dec_Wh  = (const float*)d_in[7];
    const float* dec_b   = (const float*)d_in[8];
    const float* dense_W = (const float*)d_in[9];
    const float* dense_b = (const float*)d_in[10];
    float* out = (float*)d_out;

    hipLaunchKernelGGL(seq2seq_rnn_kernel, dim3(256), dim3(512), 0, stream,
                       enc_ids, dec_ids, embed, enc_Wx, enc_Wh, enc_b,
                       dec_Wx, dec_Wh, dec_b, dense_W, dense_b, out);
}